// Round 11
// baseline (260.562 us; speedup 1.0000x reference)
//
#include <hip/hip_runtime.h>

// ROI Align (max) — R14: sequential plane-streaming with counted-vmcnt bands.
//
// Unifying result R3..R13: dur ~= FETCH / HBM_eff(pattern); the scattered
// row-segment gather sustains only 1.3-1.7 TB/s regardless of bytes
// (R10 110MB/85us, R13 190/110). Escape = R12's sequential streaming
// (61.8 MB proven) WITHOUT its barrier-drain serialization: T3/T4 —
// fixed 16-chunk bands, counted s_waitcnt vmcnt(8), raw s_barrier
// (loads fly across barriers), data-INdependent DMA counts.
//
// 256 blocks (1/CU), block = channel c = 32*(bid&7)+(bid>>3); streams
// plane (b=0,c) then (b=1,c) sequentially through a 128 KB LDS ring
// (addr = plane_byte & 131071; ring = 128 chunks of 1024 B). Per band:
// 16 chunks, 4 DMA/wave (uniform; tail clamps to chunk 237 = benign
// identical rewrite, OOB lanes exec-masked). Loop: ISSUE(s+2); vmcnt(8)
// [drains band s: exactly 8 newer DMAs exist]; s_barrier; compute boxes
// whose last row-byte lies in band s (sorted by prep kernel).
// Window proof: readable = 128-2*16 = 96 chunks >= box span 62 chunks;
// racing wave's ISSUE(s+3) overwrites chunks [16s-80,16s-64), laggard
// reads >= 16s-62 -> 3-chunk margin. Compute phase: zero global loads
// (box coords/bins + meta cached in LDS) -> vmcnt FIFO analysis exact.
//
// feature: (2, 256, 200, 304) fp32; boxes: (512,4); batch_idx: (512,) i32
// out: (512, 256, 7, 7) fp32. SPATIAL_SCALE=0.25, POOLED=7, SR=2, MODE=max.

#define SS 0.25f
#define POOLED 7

constexpr int Cc = 256;
constexpr int Hc = 200;
constexpr int Wc = 304;
constexpr int Nc = 512;

constexpr int CELLS    = 49;
constexpr int PER_BOX  = Cc * CELLS;     // 12544
constexpr int PLANE    = Hc * Wc;        // 60800 floats
constexpr int PLANE_B  = PLANE * 4;      // 243200 B
constexpr int LAST_CHUNK = 237;          // chunk 237 = bytes [242688,243712), valid half
constexpr int RING_FMASK = 32767;        // ring = 32768 floats = 128 KB
constexpr int BANDS    = 15;             // ceil(238/16)
constexpr size_t WS_NEED = (size_t)Nc * sizeof(unsigned);

// ======================= prep: band-sort boxes =======================
// meta[rank] = n | band<<9 | batch<<13, rank by (batch, band, n).
__global__ __launch_bounds__(64) void roi_prep_kernel(
    const float* __restrict__ boxes,
    const int*   __restrict__ batch_idx,
    unsigned*    __restrict__ meta)
{
    const int n = blockIdx.x, l = threadIdx.x;

    auto boxkey = [&](int j) -> unsigned {
        const float rsy = boxes[j*4+1]*SS, rey = boxes[j*4+3]*SS;
        const float bh  = fmaxf(rey - rsy, 1.0f) / 7.0f;
        const float fyL = __fadd_rn(rsy, __fmul_rn(6.75f, bh));
        const int   yL  = (int)floorf(fminf(fmaxf(fyL,0.f),(float)(Hc-1)));
        const int ymax  = min(yL + 1, Hc - 1);
        const int band  = ((ymax + 1) * (Wc*4) - 1) >> 14;   // /16384
        return (unsigned)(batch_idx[j]*16 + band);
    };

    const unsigned keyn = boxkey(n);
    int rank = 0;
    #pragma unroll
    for (int m = 0; m < Nc/64; ++m) {
        const int j = m*64 + l;
        const unsigned keyj = boxkey(j);
        const bool lt = (keyj < keyn) || (keyj == keyn && j < n);
        rank += (int)__popcll(__ballot(lt));
    }
    if (l == 0)
        meta[rank] = (unsigned)n | ((keyn & 15u) << 9)        // band
                   | ((keyn >> 4) << 13);                      // batch
}

// ============================== main =================================
__global__ __launch_bounds__(256) void roi_stream_kernel(
    const float* __restrict__ feature,
    const float* __restrict__ boxes,
    const unsigned* __restrict__ meta,
    float*       __restrict__ out)
{
    __shared__ float    ring[32768];     // 128 KB, addr = plane_byte & 131071
    __shared__ float4   boxc[Nc];        // 8 KB: {rsx, rsy, bin_w, bin_h}
    __shared__ unsigned meta_s[Nc];      // 2 KB
                                         // total 141,312 B -> 1 block/CU

    const int bid = blockIdx.x;
    const int c   = 32 * (bid & 7) + (bid >> 3);   // XCD-grouped channels
    const int tid = threadIdx.x;
    const int wv  = tid >> 6;
    const int lane = tid & 63;

    // ---- one-time: cache meta + per-box derived values in LDS ----
    for (int j = tid; j < Nc; j += 256) {
        meta_s[j] = meta[j];
        const float4 bx = *(const float4*)(boxes + j*4);
        const float rsx = bx.x*SS, rsy = bx.y*SS;
        const float rex = bx.z*SS, rey = bx.w*SS;
        float4 bc;
        bc.x = rsx; bc.y = rsy;
        bc.z = fmaxf(rex - rsx, 1.0f) / 7.0f;      // IEEE div, matches ref
        bc.w = fmaxf(rey - rsy, 1.0f) / 7.0f;
        boxc[j] = bc;
    }
    __syncthreads();                     // drains copy loads; one-time cost

#define ISSUE_BAND(PL, BAND) {                                                \
    _Pragma("unroll")                                                         \
    for (int i = 0; i < 4; ++i) {                                             \
        int k = (BAND) * 16 + wv * 4 + i;                                     \
        k = min(k, LAST_CHUNK);                                               \
        const int sb = k * 1024 + lane * 16;                                  \
        const int dst = __builtin_amdgcn_readfirstlane((k & 127) * 1024);     \
        if (sb < PLANE_B) {                                                   \
            __builtin_amdgcn_global_load_lds(                                 \
                (const __attribute__((address_space(1))) unsigned int*)       \
                    (const void*)((PL) + sb),                                 \
                (__attribute__((address_space(3))) unsigned int*)             \
                    (void*)((char*)ring + dst),                               \
                16, 0, 0);                                                    \
        }                                                                     \
    }                                                                         \
}

    int p = 0;                           // sorted-box pointer (uniform)
    for (int bph = 0; bph < 2; ++bph) {
        const char* pl = (const char*)(feature
                       + ((size_t)bph * Cc + c) * (size_t)PLANE);

        ISSUE_BAND(pl, 0)
        ISSUE_BAND(pl, 1)

        for (int s = 0; s < BANDS; ++s) {
            ISSUE_BAND(pl, s + 2)        // clamped at tail; always 4 DMAs
            // exactly 8 DMAs (bands s+1, s+2) are newer than band s's ->
            // vmcnt(8) guarantees band s drained, keeps 2 bands in flight.
            asm volatile("s_waitcnt vmcnt(8)" ::: "memory");
            __builtin_amdgcn_s_barrier();          // raw: no vmcnt(0) drain
            asm volatile("" ::: "memory");         // pin reads below barrier

            // ---- collect this band's boxes (uniform LDS walk) ----
            const int p0 = p;
            while (p < Nc) {
                const unsigned mm = meta_s[p];
                if ((int)(mm >> 13) != bph) break;
                if ((int)((mm >> 9) & 15u) > s) break;
                ++p;
            }
            const int nit = (p - p0) * CELLS;

            // ---- compute: zero global loads; ring reads & 32767 ----
            for (int i = tid; i < nit; i += 256) {
                const int jj   = (int)((unsigned)i / 49u);
                const int cell = i - jj * 49;
                const int n    = (int)(meta_s[p0 + jj] & 511u);
                const float4 bc = boxc[n];
                const int ph = cell / 7, pw = cell - ph * 7;

                float m = -INFINITY;
                #pragma unroll
                for (int sy = 0; sy < 2; ++sy) {
                    const int   sY  = ph * 2 + sy;
                    const float py  = fmaf((float)sY, 0.5f, 0.25f);
                    const float fy  = __fadd_rn(bc.y, __fmul_rn(py, bc.w));
                    const bool  vy  = (fy > -1.0f) && (fy < (float)Hc);
                    const float fyc = fminf(fmaxf(fy, 0.0f), (float)(Hc-1));
                    const int   y0  = (int)floorf(fyc);
                    float ly = fyc - (float)y0;
                    float hy = 1.0f - ly;
                    if (!vy) { ly = 0.0f; hy = 0.0f; }
                    const int r0 = y0 * Wc;
                    const int r1 = min(y0 + 1, Hc - 1) * Wc;
                    #pragma unroll
                    for (int sx = 0; sx < 2; ++sx) {
                        const int   sX  = pw * 2 + sx;
                        const float px  = fmaf((float)sX, 0.5f, 0.25f);
                        const float fx  = __fadd_rn(bc.x, __fmul_rn(px, bc.z));
                        const bool  vx  = (fx > -1.0f) && (fx < (float)Wc);
                        const float fxc = fminf(fmaxf(fx, 0.0f), (float)(Wc-1));
                        const int   x0  = (int)floorf(fxc);
                        float lx = fxc - (float)x0;
                        float hx = 1.0f - lx;
                        if (!vx) { lx = 0.0f; hx = 0.0f; }
                        const int x1 = min(x0 + 1, Wc - 1);
                        const float v00 = ring[(r0 + x0) & RING_FMASK];
                        const float v01 = ring[(r0 + x1) & RING_FMASK];
                        const float v10 = ring[(r1 + x0) & RING_FMASK];
                        const float v11 = ring[(r1 + x1) & RING_FMASK];
                        const float bil = hy*hx*v00 + hy*lx*v01
                                        + ly*hx*v10 + ly*lx*v11;
                        m = fmaxf(m, bil);
                    }
                }
                out[(size_t)n * PER_BOX + c * CELLS + cell] = m;
            }
            // no trailing barrier: ring margin proves racing ISSUE(s+3) safe
        }

        // ---- between planes: full drain, then ring is free ----
        asm volatile("s_waitcnt vmcnt(0)" ::: "memory");
        __builtin_amdgcn_s_barrier();
        asm volatile("" ::: "memory");
    }
#undef ISSUE_BAND
}

// ============== fallback: R9 kernel (if no workspace) ================
constexpr int FCG = 4, FTILES = Cc/FCG, FNSAMP = 14;
constexpr int FGRP = 264, FCH_F = 7*FGRP, FBUF_F = FCG*FCH_F;

__global__ __launch_bounds__(256) void roi_fallback_kernel(
    const float* __restrict__ feature, const float* __restrict__ boxes,
    const int* __restrict__ batch_idx, float* __restrict__ out)
{
    __shared__ float lds[2*FBUF_F];
    const int n = blockIdx.x, tid = threadIdx.x;
    const int wvv = tid >> 6, lane = tid & 63;
    const int lane16 = lane & 15, rquad = lane >> 4;

    const float rsx = boxes[n*4+0]*SS, rsy = boxes[n*4+1]*SS;
    const float rex = boxes[n*4+2]*SS, rey = boxes[n*4+3]*SS;
    const float bin_w = fmaxf(rex-rsx,1.f)/7.f, bin_h = fmaxf(rey-rsy,1.f)/7.f;
    const int b = batch_idx[n];
    const float xc0 = fminf(fmaxf(__fadd_rn(rsx,__fmul_rn(0.25f,bin_w)),0.f),(float)(Wc-1));
    const int xbase = ((int)floorf(xc0)) & ~3;
    const float xlc = fminf(fmaxf(__fadd_rn(rsx,__fmul_rn(6.75f,bin_w)),0.f),(float)(Wc-1));
    const int span = min((int)floorf(xlc)+1, Wc-1) - xbase + 1;
    const int nl4 = (span + 4) >> 2;

    int ro[7];
    #pragma unroll
    for (int it = 0; it < 7; ++it) {
        const int slot = it*4 + rquad;
        const int which = slot >= FNSAMP;
        const int sY = which ? slot - FNSAMP : slot;
        const float fy = __fadd_rn(rsy, __fmul_rn(fmaf((float)sY,0.5f,0.25f), bin_h));
        const float fyc = fminf(fmaxf(fy,0.f),(float)(Hc-1));
        const int y0 = (int)floorf(fyc);
        ro[it] = (which ? min(y0+1,Hc-1) : y0) * Wc;
    }
    const int col = min(xbase + lane16*4, Wc-4);
    const bool act = (lane16 < nl4);
    const int cell = min(lane, CELLS-1);
    const int ph = cell/POOLED, pw = cell - ph*POOLED;

    float w00[2][2], w01[2][2], w10[2][2], w11[2][2];
    int r0a[2][2], r1a[2][2];
    #pragma unroll
    for (int sy = 0; sy < 2; ++sy) {
        const int sY = ph*2+sy;
        const float fy = __fadd_rn(rsy, __fmul_rn((float)ph + ((float)sy+0.5f)*0.5f, bin_h));
        const bool vy = (fy>-1.f)&&(fy<(float)Hc);
        const float fyc = fminf(fmaxf(fy,0.f),(float)(Hc-1));
        const int y0i = (int)floorf(fyc);
        const float ly = fyc-(float)y0i, hy = 1.f-ly;
        #pragma unroll
        for (int sx = 0; sx < 2; ++sx) {
            const float fx = __fadd_rn(rsx, __fmul_rn((float)pw + ((float)sx+0.5f)*0.5f, bin_w));
            const bool vx = (fx>-1.f)&&(fx<(float)Wc);
            const float fxc = fminf(fmaxf(fx,0.f),(float)(Wc-1));
            const int x0i = (int)floorf(fxc);
            const float lx = fxc-(float)x0i, hx = 1.f-lx;
            const int c0 = x0i - xbase;
            const bool v = vy && vx;
            w00[sy][sx] = v ? hy*hx : 0.f; w01[sy][sx] = v ? hy*lx : 0.f;
            w10[sy][sx] = v ? ly*hx : 0.f; w11[sy][sx] = v ? ly*lx : 0.f;
            r0a[sy][sx] = (sY>>2)*FGRP + (sY&3)*64 + c0;
            const int s1 = FNSAMP + sY;
            r1a[sy][sx] = (s1>>2)*FGRP + (s1&3)*64 + c0;
        }
    }
    const float* __restrict__ gp0 = feature + ((size_t)b*Cc + wvv)*(size_t)PLANE;

#define FISSUE(GT, Q)                                                         \
    if (act) {                                                                \
        _Pragma("unroll")                                                     \
        for (int it = 0; it < 7; ++it) {                                      \
            const float* gsrc = (GT) + ro[it] + col;                          \
            const int lofs = __builtin_amdgcn_readfirstlane(                  \
                ((Q)*FBUF_F + wvv*FCH_F + it*FGRP)*4);                        \
            __builtin_amdgcn_global_load_lds(                                 \
                (const __attribute__((address_space(1))) unsigned int*)       \
                    (const void*)gsrc,                                        \
                (__attribute__((address_space(3))) unsigned int*)             \
                    (void*)((char*)lds + lofs), 16, 0, 0);                    \
        }                                                                     \
    }

    FISSUE(gp0, 0)
    const float* __restrict__ gnext = gp0 + (size_t)FCG*PLANE;
    for (int j = 0; j < FTILES; ++j) {
        if (j + 1 < FTILES) {
            FISSUE(gnext, ((j+1)&1))
            gnext += (size_t)FCG*PLANE;
            asm volatile("s_waitcnt vmcnt(7)" ::: "memory");
        } else {
            asm volatile("s_waitcnt vmcnt(0)" ::: "memory");
        }
        const int qb = (j&1)*FBUF_F + wvv*FCH_F;
        float m = -INFINITY;
        #pragma unroll
        for (int sy = 0; sy < 2; ++sy)
            #pragma unroll
            for (int sx = 0; sx < 2; ++sx) {
                const int a0 = qb + r0a[sy][sx], a1 = qb + r1a[sy][sx];
                const float bil = w00[sy][sx]*lds[a0] + w01[sy][sx]*lds[a0+1]
                                + w10[sy][sx]*lds[a1] + w11[sy][sx]*lds[a1+1];
                m = fmaxf(m, bil);
            }
        if (lane < CELLS)
            out[(size_t)n*PER_BOX + (size_t)(j*FCG + wvv)*CELLS + cell] = m;
    }
#undef FISSUE
}

extern "C" void kernel_launch(void* const* d_in, const int* in_sizes, int n_in,
                              void* d_out, int out_size, void* d_ws, size_t ws_size,
                              hipStream_t stream) {
    const float* feature   = (const float*)d_in[0];
    const float* boxes     = (const float*)d_in[1];
    const int*   batch_idx = (const int*)d_in[2];
    float*       out       = (float*)d_out;

    if (d_ws != nullptr && ws_size >= WS_NEED) {
        unsigned* meta = (unsigned*)d_ws;
        roi_prep_kernel<<<Nc, 64, 0, stream>>>(boxes, batch_idx, meta);
        roi_stream_kernel<<<256, 256, 0, stream>>>(feature, boxes, meta, out);
    } else {
        roi_fallback_kernel<<<Nc, 256, 0, stream>>>(feature, boxes,
                                                    batch_idx, out);
    }
}

// Round 12
// 235.720 us; speedup vs baseline: 1.1054x; 1.1054x over previous
//
#include <hip/hip_runtime.h>

// ROI Align (max) — R15: A/B role-split, CG=2, depth-2, 16 waves/CU.
//
// Ledger synthesis R3..R14: gather-pattern HBM rate scales with in-flight
// loads — R3 (20 waves/CU) 3.2 TB/s, R6 (24) 2.4, R10 (8) 1.3. R10's 85 us
// on 110 MB was MLP-limited (~13 KB in flight vs ~10 KB latency-BW minimum,
// no queue margin), not an HBM-pattern ceiling. R14's streaming died on
// stores polluting the vmcnt FIFO + 4 waves/CU.
//
// R15 combines all three proven wins: low fetch (R10 perm), low VALU
// (hoisted weights/offsets), high MLP: R13's verified A/B wave split
// (A: ph0-3, 16 slots, NI=4 DMA; B: ph4-6, 12 slots, NI=3) at CG=2,
// depth-2 -> LDS 29,120 B; grid = 512 boxes x 2 channel-halves = 1024
// blocks -> 4 blocks x 4 waves = 16 waves/CU, ~26 KB in flight.
// Store-FIFO-exact waits: flush vmcnt(0) once; peeled iter0 vmcnt(NI);
// steady vmcnt(NI+1) = loads(t+1)+store(t-1) -> drains tile t, never
// waits store acks; final vmcnt(1). XCD map: bid=(half<<9)|i, XCD=i&7.
//
// feature: (2, 256, 200, 304) fp32; boxes: (512,4); batch_idx: (512,) i32
// out: (512, 256, 7, 7) fp32. SPATIAL_SCALE=0.25, POOLED=7, SR=2, MODE=max.

#define SS 0.25f
#define POOLED 7

constexpr int Cc = 256;
constexpr int Hc = 200;
constexpr int Wc = 304;
constexpr int Nc = 512;

constexpr int CELLS   = 49;
constexpr int PER_BOX = Cc * CELLS;      // 12544
constexpr int PLANE   = Hc * Wc;         // 60800
constexpr int TILES   = 64;              // 2 channels/tile over a 128-ch half
constexpr int GRPF    = 260;             // floats per 4-slot group (1040 B)
constexpr int BUF_A   = 4 * GRPF;        // 1040 floats (role A buffer)
constexpr int BUF_B   = 3 * GRPF;        // 780  floats (role B buffer)
constexpr int CH_F    = 2 * (BUF_A + BUF_B); // 3640 floats per channel
constexpr int LDS_F   = 2 * CH_F;        // 7280 floats = 29,120 B -> 4+ blk/CU
constexpr size_t WS_NEED = (size_t)Nc * sizeof(int);

// ====================== box spatial-rank kernel ======================
// Bijective perm sorted by (batch, y-band, index) -> XCD clustering (R10).
__global__ __launch_bounds__(64) void box_rank_kernel(
    const float* __restrict__ boxes,
    const int*   __restrict__ batch_idx,
    int*         __restrict__ perm)
{
    const int n = blockIdx.x;
    const int l = threadIdx.x;

    const float cyn  = (boxes[n * 4 + 1] + boxes[n * 4 + 3]) * (0.5f * SS);
    const int  bandn = min(3, max(0, (int)(cyn * (4.0f / (float)Hc))));
    const int  keyn  = batch_idx[n] * 4 + bandn;

    int rank = 0;
    #pragma unroll
    for (int m = 0; m < Nc / 64; ++m) {
        const int j = m * 64 + l;
        const float cyj  = (boxes[j * 4 + 1] + boxes[j * 4 + 3]) * (0.5f * SS);
        const int  bandj = min(3, max(0, (int)(cyj * (4.0f / (float)Hc))));
        const int  keyj  = batch_idx[j] * 4 + bandj;
        const bool lt = (keyj < keyn) || (keyj == keyn && j < n);
        rank += (int)__popcll(__ballot(lt));
    }
    if (l == 0) perm[rank] = n;
}

// ============================== main =================================
template <bool USE_PERM>
__global__ __launch_bounds__(256) void roi_align_max_kernel(
    const float* __restrict__ feature,
    const float* __restrict__ boxes,
    const int*   __restrict__ batch_idx,
    const int*   __restrict__ perm,
    float*       __restrict__ out)
{
    __shared__ float lds[LDS_F];         // 29,120 B

    const int bid  = blockIdx.x;
    const int half = bid >> 9;           // channel half 0/1
    const int i0   = bid & 511;          // XCD = i0 & 7 for both halves
    const int n    = USE_PERM ? perm[(i0 & 7) * 64 + (i0 >> 3)] : i0;
    const int tid  = threadIdx.x;
    const int wv   = tid >> 6;
    const int lane = tid & 63;
    const int chl  = wv >> 1;            // channel-local 0..1
    const int role = wv & 1;             // 0 = ph0-3 (A), 1 = ph4-6 (B)
    const int NI    = role ? 3 : 4;      // DMA instrs per tile
    const int BUF   = role ? BUF_B : BUF_A;
    const int wbase = chl * CH_F + (role ? 2 * BUF_A : 0);
    const int HALF  = role ? 6 : 8;      // y0 slot count
    const int SYB   = role ? 8 : 0;      // first sample-y handled
    const int NCELL = role ? 21 : 28;
    const int lane16 = lane & 15;
    const int rquad  = lane >> 4;

    // ---- box math (block-uniform -> scalar) ----
    const float rsx = boxes[n * 4 + 0] * SS;
    const float rsy = boxes[n * 4 + 1] * SS;
    const float rex = boxes[n * 4 + 2] * SS;
    const float rey = boxes[n * 4 + 3] * SS;
    const float roi_w = fmaxf(rex - rsx, 1.0f);
    const float roi_h = fmaxf(rey - rsy, 1.0f);
    const float bin_w = roi_w / (float)POOLED;
    const float bin_h = roi_h / (float)POOLED;
    const int   b     = batch_idx[n];

    const float x_first = __fadd_rn(rsx, __fmul_rn(0.25f, bin_w));
    const float xc0     = fminf(fmaxf(x_first, 0.0f), (float)(Wc - 1));
    const int   xbase   = ((int)floorf(xc0)) & ~3;

    const float x_last = __fadd_rn(rsx, __fmul_rn(6.75f, bin_w));
    const float xlc    = fminf(fmaxf(x_last, 0.0f), (float)(Wc - 1));
    const int   x0l    = (int)floorf(xlc);
    const int   xlastc = min(x0l + 1, Wc - 1);
    const int   span   = xlastc - xbase + 1;      // <= 54
    const int   nl4    = (span + 4) >> 2;         // <= 14 float4 lanes

    // ---- staging rows: DMA instr i writes slots ls = 4i+rquad ----
    int ro[4];
    #pragma unroll
    for (int i = 0; i < 4; ++i) {
        const int ls    = i * 4 + rquad;
        const int which = ls >= HALF;
        const int sY    = SYB + (which ? ls - HALF : ls);
        const float py  = fmaf((float)sY, 0.5f, 0.25f);
        const float fy  = __fadd_rn(rsy, __fmul_rn(py, bin_h));
        const float fyc = fminf(fmaxf(fy, 0.0f), (float)(Hc - 1));
        const int   y0  = (int)floorf(fyc);
        ro[i] = (which ? min(y0 + 1, Hc - 1) : y0) * Wc;
    }
    const int  col = min(xbase + lane16 * 4, Wc - 4);
    const bool act = (lane16 < nl4);

    // ---- compute metadata: lane -> cell within this role's ph range ----
    const int cidx = min(lane, NCELL - 1);
    const int ph   = (role ? 4 : 0) + cidx / 7;
    const int pw   = cidx % 7;

    float w00[2][2], w01[2][2], w10[2][2], w11[2][2];
    int   a0t[2][2], a1t[2][2];          // buffer-relative float offsets
    #pragma unroll
    for (int sy = 0; sy < 2; ++sy) {
        const int   sY  = ph * 2 + sy;
        const float py  = (float)ph + ((float)sy + 0.5f) * 0.5f;
        const float fy  = __fadd_rn(rsy, __fmul_rn(py, bin_h));
        const bool  vy  = (fy > -1.0f) && (fy < (float)Hc);
        const float fyc = fminf(fmaxf(fy, 0.0f), (float)(Hc - 1));
        const int   y0i = (int)floorf(fyc);
        const float ly  = fyc - (float)y0i;
        const float hy  = 1.0f - ly;
        #pragma unroll
        for (int sx = 0; sx < 2; ++sx) {
            const float px  = (float)pw + ((float)sx + 0.5f) * 0.5f;
            const float fx  = __fadd_rn(rsx, __fmul_rn(px, bin_w));
            const bool  vx  = (fx > -1.0f) && (fx < (float)Wc);
            const float fxc = fminf(fmaxf(fx, 0.0f), (float)(Wc - 1));
            const int   x0i = (int)floorf(fxc);
            const float lx  = fxc - (float)x0i;
            const float hx  = 1.0f - lx;
            const int   c0  = x0i - xbase;
            const bool  v   = vy && vx;          // validity folded into weights
            w00[sy][sx] = v ? hy * hx : 0.0f;
            w01[sy][sx] = v ? hy * lx : 0.0f;
            w10[sy][sx] = v ? ly * hx : 0.0f;
            w11[sy][sx] = v ? ly * lx : 0.0f;
            const int lsY = sY - SYB;            // 0..HALF-1
            const int ls0 = lsY;                 // y0 slot
            const int ls1 = lsY + HALF;          // y1 slot
            a0t[sy][sx] = (ls0 >> 2) * GRPF + (ls0 & 3) * 64 + c0;
            a1t[sy][sx] = (ls1 >> 2) * GRPF + (ls1 & 3) * 64 + c0;
        }
    }

#define ISSUE(PTR, QOFF)                                                      \
    if (act) {                                                                \
        for (int i = 0; i < NI; ++i) {                                        \
            const float* gsrc = (PTR) + ro[i] + col;                          \
            const int lofs = __builtin_amdgcn_readfirstlane(                  \
                (wbase + (QOFF) + i * GRPF) * 4);                             \
            __builtin_amdgcn_global_load_lds(                                 \
                (const __attribute__((address_space(1))) unsigned int*)       \
                    (const void*)gsrc,                                        \
                (__attribute__((address_space(3))) unsigned int*)             \
                    (void*)((char*)lds + lofs),                               \
                16, 0, 0);                                                    \
        }                                                                     \
    }

#define COMPUTE(QSEL)                                                         \
    {                                                                         \
        const int qb = wbase + (QSEL) * BUF;                                  \
        float m = -INFINITY;                                                  \
        _Pragma("unroll")                                                     \
        for (int sy = 0; sy < 2; ++sy) {                                      \
            _Pragma("unroll")                                                 \
            for (int sx = 0; sx < 2; ++sx) {                                  \
                const int a0 = qb + a0t[sy][sx];                              \
                const int a1 = qb + a1t[sy][sx];                              \
                const float bil = w00[sy][sx] * lds[a0]                       \
                                + w01[sy][sx] * lds[a0 + 1]                   \
                                + w10[sy][sx] * lds[a1]                       \
                                + w11[sy][sx] * lds[a1 + 1];                  \
                m = fmaxf(m, bil);                                            \
            }                                                                 \
        }                                                                     \
        if (lane < NCELL) *outp = m;                                          \
        outp += 2 * CELLS;                                                    \
    }

    // channel for tile t = 128*half + 2t + chl
    const float* gp = feature
        + ((size_t)b * Cc + 128 * half + chl) * (size_t)PLANE;
    float* outp = out + (size_t)n * PER_BOX
                + (size_t)(128 * half + chl) * CELLS
                + (role ? 28 : 0) + cidx;

    // ---- flush: make the vmcnt FIFO provably empty before the pipeline ----
    asm volatile("s_waitcnt vmcnt(0)" ::: "memory");

    // prologue: tile 0 -> buf 0
    ISSUE(gp, 0)
    gp += (size_t)2 * PLANE;

    // iter 0 (peeled): FIFO = loads(0), loads(1) -> vmcnt(NI) drains tile 0
    ISSUE(gp, BUF)
    gp += (size_t)2 * PLANE;
    if (role == 0) asm volatile("s_waitcnt vmcnt(4)" ::: "memory");
    else           asm volatile("s_waitcnt vmcnt(3)" ::: "memory");
    COMPUTE(0)

    // steady: FIFO = loads(t), store(t-1), loads(t+1) -> vmcnt(NI+1)
    // drains tile t's loads; never waits on store acks.
    for (int t = 1; t <= TILES - 2; ++t) {
        ISSUE(gp, ((t + 1) & 1) * BUF)
        gp += (size_t)2 * PLANE;
        if (role == 0) asm volatile("s_waitcnt vmcnt(5)" ::: "memory");
        else           asm volatile("s_waitcnt vmcnt(4)" ::: "memory");
        COMPUTE(t & 1)
    }

    // final: FIFO = loads(T-1), store(T-2) -> vmcnt(1) drains loads(T-1)
    asm volatile("s_waitcnt vmcnt(1)" ::: "memory");
    COMPUTE((TILES - 1) & 1)
#undef ISSUE
#undef COMPUTE
}

extern "C" void kernel_launch(void* const* d_in, const int* in_sizes, int n_in,
                              void* d_out, int out_size, void* d_ws, size_t ws_size,
                              hipStream_t stream) {
    const float* feature   = (const float*)d_in[0];
    const float* boxes     = (const float*)d_in[1];
    const int*   batch_idx = (const int*)d_in[2];
    float*       out       = (float*)d_out;

    const int grid = 2 * Nc;             // 512 boxes x 2 channel-halves
    if (d_ws != nullptr && ws_size >= WS_NEED) {
        int* perm = (int*)d_ws;
        box_rank_kernel<<<Nc, 64, 0, stream>>>(boxes, batch_idx, perm);
        roi_align_max_kernel<true><<<grid, 256, 0, stream>>>(
            feature, boxes, batch_idx, perm, out);
    } else {
        roi_align_max_kernel<false><<<grid, 256, 0, stream>>>(
            feature, boxes, batch_idx, nullptr, out);
    }
}